// Round 7
// baseline (101.833 us; speedup 1.0000x reference)
//
#include <hip/hip_runtime.h>

// Fast discrete Radon transform (exact, wrap-around shears), radix-16:
//   case A (m<512):   R_m[t]  = sum_y img[(t - m*y) & 511, y]
//   case B (m>=512):  R'_a[t] = sum_x img[x, (t - 2a*x) & 511], a = m-512
// out = R * (1/sqrt(512)), imag exactly 0.
//
// Stages: 1 ->(init, radix-2, case A only) 2 ->(radix-16) 32 ->(radix-16, fused output) 512.
// Case B: radix-2 fused into pass1's staging loads (no B0 buffer).
// k_init: all 4 transpose tiles resident (33KB LDS), ONE barrier, 2 blocks/CU.
// pass2: NO LDS — gather directly from global (coalesced; per-XCD working
// set 3MB fits L2), removing the stage->barrier->gather phase serialization.
// LDS/global-gather redundancy elimination in pass1/pass2 (bit-exact).

#define NN 512
#define MU 768
#define MASK 511
#define SCALE 0.04419417382415922f  // 1/sqrt(512)

// ---- init: case A transpose + radix-2; img read exactly once -------------
// Block = (x-tile pair {x0,x0+256}) x (32-wide w tile). Tiles:
//   T0=(x0,w0) T1=(x0,w0+256) T2=(x1,w0) T3=(x1,w0+256)
// Outputs: cls0@x0=T0+T1, cls1@x0=T0+T3, cls0@x1=T2+T3, cls1@x1=T2+T1.
__global__ __launch_bounds__(512) void k_init(const float* __restrict__ img,
                                              float* __restrict__ A0) {
  __shared__ float T[4][64][33];
  const int bx = blockIdx.x, b = blockIdx.y;
  const int xp = bx >> 3, wt = bx & 7;       // xp<4, wt<8
  const int x0 = xp * 64, x1 = x0 + 256, w0 = wt * 32;
  const float* src = img + (size_t)b * NN * NN;
  float* dst = A0 + (size_t)b * (512 * NN);

  for (int idx = threadIdx.x; idx < 2048; idx += 512) {
    const int tile = idx >> 9;               // 0..3
    const int r = (idx >> 3) & 63, c4 = (idx & 7) << 2;
    const int xb = (tile & 2) ? x1 : x0;
    const int wb = (tile & 1) ? (w0 + 256) : w0;
    const float4 v = *(const float4*)&src[(size_t)(xb + r) * NN + wb + c4];
    T[tile][r][c4]     = v.x;
    T[tile][r][c4 + 1] = v.y;
    T[tile][r][c4 + 2] = v.z;
    T[tile][r][c4 + 3] = v.w;
  }
  __syncthreads();
  for (int idx = threadIdx.x; idx < 2048; idx += 512) {
    const int s = idx >> 9;                  // 0..3 output set
    const int wl = (idx >> 4) & 31, x4 = (idx & 15) << 2;
    const int ta = (s & 2) ? 2 : 0;
    const int tb = (s == 0) ? 1 : (s == 1) ? 3 : (s == 2) ? 3 : 1;
    const int rbase = ((s & 1) ? 256 : 0) + w0;
    const int cbase = (s & 2) ? x1 : x0;
    float4 a;
    a.x = T[ta][x4][wl]     + T[tb][x4][wl];
    a.y = T[ta][x4 + 1][wl] + T[tb][x4 + 1][wl];
    a.z = T[ta][x4 + 2][wl] + T[tb][x4 + 2][wl];
    a.w = T[ta][x4 + 3][wl] + T[tb][x4 + 3][wl];
    *(float4*)&dst[(size_t)(rbase + wl) * NN + cbase + x4] = a;
  }
}

// ---- pass 1: stage 2 -> 32 (H=16, shifts %16==0 -> float4 LDS reads) -----
// Per thread: j = 4*jj + g, C = C0 + 8*jj, shift(jj) = 128*bb*jj mod 512
// -> distinct reads per bb: bb%4==0 -> 1, bb%4==2 -> 2, odd -> 4 (44 vs 64).
__global__ __launch_bounds__(512) void k_pass1(const float* __restrict__ A0,
                                               const float* __restrict__ img,
                                               float* __restrict__ A1,
                                               float* __restrict__ B1) {
  __shared__ float L[16 * 512];
  const int bx = blockIdx.x, b = blockIdx.y;
  const int t = threadIdx.x;
  const bool isB = bx >= 32;
  const int c = isB ? 0 : (bx >> 4);
  const int w = isB ? (bx - 32) : (bx & 15);
  if (isB) {
    const float4* s4 = (const float4*)(img + (size_t)b * NN * NN);
    float4* l4 = (float4*)L;
    for (int it = 0; it < 4; ++it) {
      int flat = it * 512 + t;  // 2048 float4
      int lrow = flat >> 7, col = flat & 127;
      float4 u = s4[(w + 16 * lrow) * 128 + col];
      float4 v = s4[(w + 16 * lrow + 256) * 128 + col];
      u.x += v.x; u.y += v.y; u.z += v.z; u.w += v.w;
      l4[lrow * 128 + col] = u;
    }
  } else {
    const float4* s4 = (const float4*)(A0 + (size_t)b * 512 * NN);
    float4* l4 = (float4*)L;
    const int pbase = c * 256 + w;  // parent row bb: pbase + 16*bb
    for (int it = 0; it < 4; ++it) {
      int flat = it * 512 + t;  // 2048 float4
      int lrow = flat >> 7, col = flat & 127;
      l4[lrow * 128 + col] = s4[(pbase + 16 * lrow) * 128 + col];
    }
  }
  __syncthreads();
  const int g = t >> 7;            // 0..3
  const int x4 = (t & 127) * 4;
  const int C0 = isB ? (2 * g) : (c + 2 * g);
  float* outA = A1 + (size_t)b * 512 * NN;
  float* outB = B1 + (size_t)b * 256 * NN;
  float4 acc[4];
#pragma unroll
  for (int jj = 0; jj < 4; ++jj) acc[jj] = make_float4(0.f, 0.f, 0.f, 0.f);
#pragma unroll
  for (int bb = 0; bb < 16; ++bb) {
    const int p = ((bb & 3) == 0) ? 1 : (((bb & 1) == 0) ? 2 : 4);
    const int step = (128 * bb) & MASK;
    int base = (x4 - C0 * bb * 16) & MASK;  // %4==0: no wrap split
    float4 v[4];
#pragma unroll
    for (int k = 0; k < 4; ++k)
      if (k < p) {
        v[k] = *(const float4*)&L[bb * 512 + base];
        base = (base - step) & MASK;
      }
#pragma unroll
    for (int jj = 0; jj < 4; ++jj) {
      const float4 u = v[jj & (p - 1)];
      acc[jj].x += u.x; acc[jj].y += u.y; acc[jj].z += u.z; acc[jj].w += u.w;
    }
  }
#pragma unroll
  for (int jj = 0; jj < 4; ++jj) {
    const int j = 4 * jj + g;
    const int C = C0 + 8 * jj;
    const int orow = isB ? (j * 16 + w) : (C * 16 + w);
    float* op = isB ? outB : outA;
    *(float4*)&op[(size_t)orow * NN + x4] = acc[jj];
  }
}

// ---- pass 2: stage 32 -> 512 (H=1) + fused scale/float2 output -----------
// No LDS: gather directly from global. Consecutive lanes -> consecutive
// addresses (wrap splits a wave into <=2 segments). Per-block input 32KB;
// 96 blocks/XCD * 32KB = 3MB fits L2, so re-reads are L2 hits.
// shift(j) = 32*bb*j mod 512 -> distinct reads per bb: 16/gcd(bb,16)
// (bb=0:1, bb=8:2, bb%4==0:4, bb%2==0:8, odd:16) => 171 vs 256 reads.
__global__ __launch_bounds__(512) void k_pass2(const float* __restrict__ A1,
                                               const float* __restrict__ B1,
                                               float2* __restrict__ out) {
  const int bx = blockIdx.x, b = blockIdx.y;
  const int t = threadIdx.x;  // = x
  const bool isB = bx >= 32;
  const int c = isB ? 2 * (bx - 32) : bx;
  const float* __restrict__ in =
      isB ? (B1 + (size_t)b * 256 * NN + (size_t)(c >> 1) * 16 * NN)
          : (A1 + (size_t)b * 512 * NN + (size_t)c * 16 * NN);
  float acc[16];
#pragma unroll
  for (int j = 0; j < 16; ++j) acc[j] = 0.f;
#pragma unroll
  for (int bb = 0; bb < 16; ++bb) {
    const int p = (bb == 0) ? 1
                : ((bb & 1) ? 16 : ((bb & 2) ? 8 : ((bb & 4) ? 4 : 2)));
    const int step = (32 * bb) & MASK;
    const float* __restrict__ row = in + bb * NN;
    int base = (t - c * bb) & MASK;
    float v[16];
#pragma unroll
    for (int k = 0; k < 16; ++k)
      if (k < p) {
        v[k] = row[base];            // lanes consecutive -> coalesced
        base = (base - step) & MASK;
      }
#pragma unroll
    for (int j = 0; j < 16; ++j) acc[j] += v[j & (p - 1)];
  }
#pragma unroll
  for (int j = 0; j < 16; ++j) {
    int m = isB ? (512 + (c >> 1) + 16 * j) : (c + 32 * j);
    float2 o; o.x = acc[j] * SCALE; o.y = 0.f;
    out[((size_t)b * MU + m) * NN + t] = o;
  }
}

// ================= fallback: round-1 direct shear-sum =====================
#define TM 16
#define YT 16
#define LDS_STRIDE 516
__global__ __launch_bounds__(512) void drt_main(const float* __restrict__ img,
                                                float* __restrict__ out) {
  __shared__ float rows[YT * LDS_STRIDE];
  const int b = blockIdx.y;
  const int tile = blockIdx.x;
  const int t = threadIdx.x;
  const bool caseB = (tile >= 32);
  const int a0 = caseB ? (tile - 32) * TM : tile * TM;
  const float* __restrict__ src = img + (size_t)b * (NN * NN);
  const int slope0 = caseB ? (2 * a0) : a0;
  const int dslope = caseB ? 2 : 1;
  float acc[TM];
#pragma unroll
  for (int i = 0; i < TM; ++i) acc[i] = 0.0f;
  for (int y0 = 0; y0 < NN; y0 += YT) {
    __syncthreads();
    if (caseB) {
#pragma unroll
      for (int r = 0; r < YT; ++r) rows[r * LDS_STRIDE + t] = src[(y0 + r) * NN + t];
    } else {
#pragma unroll
      for (int rep = 0; rep < YT; ++rep) {
        int idx = rep * NN + t;
        int xx = idx >> 4, cc = idx & 15;
        rows[cc * LDS_STRIDE + xx] = src[xx * NN + y0 + cc];
      }
    }
    __syncthreads();
#pragma unroll 4
    for (int r = 0; r < YT; ++r) {
      const int v = y0 + r;
      int base = t - slope0 * v;
      const int step = dslope * v;
      const float* __restrict__ rowp = rows + r * LDS_STRIDE;
#pragma unroll
      for (int i = 0; i < TM; ++i) { acc[i] += rowp[base & MASK]; base -= step; }
    }
  }
  const int m = caseB ? (NN + a0) : a0;
  float2* outp = (float2*)out;
#pragma unroll
  for (int i = 0; i < TM; ++i) {
    float2 vv; vv.x = acc[i] * SCALE; vv.y = 0.0f;
    outp[((size_t)b * MU + (m + i)) * NN + t] = vv;
  }
}

extern "C" void kernel_launch(void* const* d_in, const int* in_sizes, int n_in,
                              void* d_out, int out_size, void* d_ws, size_t ws_size,
                              hipStream_t stream) {
  const float* img = (const float*)d_in[0];
  if (ws_size < (size_t)42 * 1024 * 1024) {
    drt_main<<<dim3(48, 16), dim3(512), 0, stream>>>(img, (float*)d_out);
    return;
  }
  float* W  = (float*)d_ws;
  float* A0 = W;                 // 16 x 512 x 512
  float* A1 = W + 4194304;       // 16 x 512 x 512
  float* B1 = W + 8388608;       // 16 x 256 x 512

  k_init <<<dim3(32, 16), dim3(512), 0, stream>>>(img, A0);
  k_pass1<<<dim3(48, 16), dim3(512), 0, stream>>>(A0, img, A1, B1);
  k_pass2<<<dim3(48, 16), dim3(512), 0, stream>>>(A1, B1, (float2*)d_out);
}

// Round 9
// 96.604 us; speedup vs baseline: 1.0541x; 1.0541x over previous
//
#include <hip/hip_runtime.h>

// Fast discrete Radon transform (exact, wrap-around shears), radix-16:
//   case A (m<512):   R_m[t]  = sum_y img[(t - m*y) & 511, y]
//   case B (m>=512):  R'_a[t] = sum_x img[x, (t - 2a*x) & 511], a = m-512
// out = R * (1/sqrt(512)), imag exactly 0.
//
// Stages: 1 ->(init, radix-2, case A only) 2 ->(radix-16) 32 ->(radix-16, fused output) 512.
// K1 = k_init (case-A transpose+radix-2) MERGED with pass1-caseB (independent;
//      both read img back-to-back -> second read is L3-served).
// K2 = pass1-caseA (A0 -> A1). K3 = pass2 (LDS-staged; nontemporal out).
// LDS-gather redundancy elimination in pass1/pass2 (bit-exact).

#define NN 512
#define MU 768
#define MASK 511
#define SCALE 0.04419417382415922f  // 1/sqrt(512)

typedef float f32x2 __attribute__((ext_vector_type(2)));

// ---- K1: blocks 0..31 = init (transpose + radix-2, one barrier);
//          blocks 32..47 = pass1 case-B (img radix-2 fused staging) ---------
__global__ __launch_bounds__(512) void k_init_p1b(const float* __restrict__ img,
                                                  float* __restrict__ A0,
                                                  float* __restrict__ B1) {
  __shared__ float S[4 * 64 * 33];  // 33.8 KB (init); p1B uses 32 KB as L
  const int bx = blockIdx.x, b = blockIdx.y;
  const int t = threadIdx.x;
  const float* src = img + (size_t)b * NN * NN;

  if (bx < 32) {
    // ---- init: tiles T0=(x0,w0) T1=(x0,w0+256) T2=(x1,w0) T3=(x1,w0+256)
    // outputs: cls0@x0=T0+T1, cls1@x0=T0+T3, cls0@x1=T2+T3, cls1@x1=T2+T1.
    float (*T)[64][33] = (float (*)[64][33])S;
    const int xp = bx >> 3, wt = bx & 7;     // xp<4, wt<8
    const int x0 = xp * 64, x1 = x0 + 256, w0 = wt * 32;
    float* dst = A0 + (size_t)b * (512 * NN);

    for (int idx = t; idx < 2048; idx += 512) {
      const int tile = idx >> 9;             // 0..3
      const int r = (idx >> 3) & 63, c4 = (idx & 7) << 2;
      const int xb = (tile & 2) ? x1 : x0;
      const int wb = (tile & 1) ? (w0 + 256) : w0;
      const float4 v = *(const float4*)&src[(size_t)(xb + r) * NN + wb + c4];
      T[tile][r][c4]     = v.x;
      T[tile][r][c4 + 1] = v.y;
      T[tile][r][c4 + 2] = v.z;
      T[tile][r][c4 + 3] = v.w;
    }
    __syncthreads();
    for (int idx = t; idx < 2048; idx += 512) {
      const int s = idx >> 9;                // 0..3 output set
      const int wl = (idx >> 4) & 31, x4 = (idx & 15) << 2;
      const int ta = (s & 2) ? 2 : 0;
      const int tb = (s == 0) ? 1 : (s == 1) ? 3 : (s == 2) ? 3 : 1;
      const int rbase = ((s & 1) ? 256 : 0) + w0;
      const int cbase = (s & 2) ? x1 : x0;
      float4 a;
      a.x = T[ta][x4][wl]     + T[tb][x4][wl];
      a.y = T[ta][x4 + 1][wl] + T[tb][x4 + 1][wl];
      a.z = T[ta][x4 + 2][wl] + T[tb][x4 + 2][wl];
      a.w = T[ta][x4 + 3][wl] + T[tb][x4 + 3][wl];
      *(float4*)&dst[(size_t)(rbase + wl) * NN + cbase + x4] = a;
    }
  } else {
    // ---- pass1 case-B: w = bx-32; radix-2 over x fused into staging.
    float* L = S;                            // 16*512 floats
    const int w = bx - 32;
    {
      const float4* s4 = (const float4*)src;
      float4* l4 = (float4*)L;
      for (int it = 0; it < 4; ++it) {
        int flat = it * 512 + t;  // 2048 float4
        int lrow = flat >> 7, col = flat & 127;
        float4 u = s4[(w + 16 * lrow) * 128 + col];
        float4 v = s4[(w + 16 * lrow + 256) * 128 + col];
        u.x += v.x; u.y += v.y; u.z += v.z; u.w += v.w;
        l4[lrow * 128 + col] = u;
      }
    }
    __syncthreads();
    const int g = t >> 7;            // 0..3
    const int x4 = (t & 127) * 4;
    const int C0 = 2 * g;
    float* outB = B1 + (size_t)b * 256 * NN;
    float4 acc[4];
#pragma unroll
    for (int jj = 0; jj < 4; ++jj) acc[jj] = make_float4(0.f, 0.f, 0.f, 0.f);
#pragma unroll
    for (int bb = 0; bb < 16; ++bb) {
      const int p = ((bb & 3) == 0) ? 1 : (((bb & 1) == 0) ? 2 : 4);
      const int step = (128 * bb) & MASK;
      int base = (x4 - C0 * bb * 16) & MASK;  // %4==0: no wrap split
      float4 v[4];
#pragma unroll
      for (int k = 0; k < 4; ++k)
        if (k < p) {
          v[k] = *(const float4*)&L[bb * 512 + base];
          base = (base - step) & MASK;
        }
#pragma unroll
      for (int jj = 0; jj < 4; ++jj) {
        const float4 u = v[jj & (p - 1)];
        acc[jj].x += u.x; acc[jj].y += u.y; acc[jj].z += u.z; acc[jj].w += u.w;
      }
    }
#pragma unroll
    for (int jj = 0; jj < 4; ++jj) {
      const int j = 4 * jj + g;
      *(float4*)&outB[(size_t)(j * 16 + w) * NN + x4] = acc[jj];
    }
  }
}

// ---- K2: pass1 case-A: stage 2 -> 32 (H=16, float4 LDS reads) ------------
// Per thread: j = 4*jj + g, C = C0 + 8*jj, shift(jj) = 128*bb*jj mod 512
// -> distinct reads per bb: bb%4==0 -> 1, bb%4==2 -> 2, odd -> 4 (44 vs 64).
__global__ __launch_bounds__(512) void k_pass1A(const float* __restrict__ A0,
                                                float* __restrict__ A1) {
  __shared__ float L[16 * 512];
  const int bx = blockIdx.x, b = blockIdx.y;
  const int t = threadIdx.x;
  const int c = bx >> 4;
  const int w = bx & 15;
  {
    const float4* s4 = (const float4*)(A0 + (size_t)b * 512 * NN);
    float4* l4 = (float4*)L;
    const int pbase = c * 256 + w;  // parent row bb: pbase + 16*bb
    for (int it = 0; it < 4; ++it) {
      int flat = it * 512 + t;  // 2048 float4
      int lrow = flat >> 7, col = flat & 127;
      l4[lrow * 128 + col] = s4[(pbase + 16 * lrow) * 128 + col];
    }
  }
  __syncthreads();
  const int g = t >> 7;            // 0..3
  const int x4 = (t & 127) * 4;
  const int C0 = c + 2 * g;
  float* outA = A1 + (size_t)b * 512 * NN;
  float4 acc[4];
#pragma unroll
  for (int jj = 0; jj < 4; ++jj) acc[jj] = make_float4(0.f, 0.f, 0.f, 0.f);
#pragma unroll
  for (int bb = 0; bb < 16; ++bb) {
    const int p = ((bb & 3) == 0) ? 1 : (((bb & 1) == 0) ? 2 : 4);
    const int step = (128 * bb) & MASK;
    int base = (x4 - C0 * bb * 16) & MASK;  // %4==0: no wrap split
    float4 v[4];
#pragma unroll
    for (int k = 0; k < 4; ++k)
      if (k < p) {
        v[k] = *(const float4*)&L[bb * 512 + base];
        base = (base - step) & MASK;
      }
#pragma unroll
    for (int jj = 0; jj < 4; ++jj) {
      const float4 u = v[jj & (p - 1)];
      acc[jj].x += u.x; acc[jj].y += u.y; acc[jj].z += u.z; acc[jj].w += u.w;
    }
  }
#pragma unroll
  for (int jj = 0; jj < 4; ++jj) {
    const int C = C0 + 8 * jj;
    *(float4*)&outA[(size_t)(C * 16 + w) * NN + x4] = acc[jj];
  }
}

// ---- K3: pass 2: stage 32 -> 512 (H=1) + fused scale/float2 output -------
// shift(j) = 32*bb*j mod 512 -> distinct reads per bb: 16/gcd(bb,16)
// (bb=0:1, bb=8:2, bb%4==0:4, bb%2==0:8, odd:16) => 171 vs 256 reads.
// Output is never re-read -> nontemporal stores (don't evict A1/B1).
__global__ __launch_bounds__(512) void k_pass2(const float* __restrict__ A1,
                                               const float* __restrict__ B1,
                                               float2* __restrict__ out) {
  __shared__ float L[16 * 512];
  const int bx = blockIdx.x, b = blockIdx.y;
  const int t = threadIdx.x;  // = x
  const bool isB = bx >= 32;
  const int c = isB ? 2 * (bx - 32) : bx;
  const float* in = isB ? (B1 + (size_t)b * 256 * NN + (size_t)(c >> 1) * 16 * NN)
                        : (A1 + (size_t)b * 512 * NN + (size_t)c * 16 * NN);
  {
    const float4* s4 = (const float4*)in;
    float4* l4 = (float4*)L;
    for (int it = 0; it < 4; ++it) l4[it * 512 + t] = s4[it * 512 + t];
  }
  __syncthreads();
  float acc[16];
#pragma unroll
  for (int j = 0; j < 16; ++j) acc[j] = 0.f;
#pragma unroll
  for (int bb = 0; bb < 16; ++bb) {
    const int p = (bb == 0) ? 1
                : ((bb & 1) ? 16 : ((bb & 2) ? 8 : ((bb & 4) ? 4 : 2)));
    const int step = (32 * bb) & MASK;
    const float* row = L + bb * 512;
    int base = (t - c * bb) & MASK;
    float v[16];
#pragma unroll
    for (int k = 0; k < 16; ++k)
      if (k < p) {
        v[k] = row[base];            // consecutive lanes -> consecutive banks
        base = (base - step) & MASK;
      }
#pragma unroll
    for (int j = 0; j < 16; ++j) acc[j] += v[j & (p - 1)];
  }
#pragma unroll
  for (int j = 0; j < 16; ++j) {
    int m = isB ? (512 + (c >> 1) + 16 * j) : (c + 32 * j);
    f32x2 o; o.x = acc[j] * SCALE; o.y = 0.f;
    __builtin_nontemporal_store(o, (f32x2*)&out[((size_t)b * MU + m) * NN + t]);
  }
}

// ================= fallback: round-1 direct shear-sum =====================
#define TM 16
#define YT 16
#define LDS_STRIDE 516
__global__ __launch_bounds__(512) void drt_main(const float* __restrict__ img,
                                                float* __restrict__ out) {
  __shared__ float rows[YT * LDS_STRIDE];
  const int b = blockIdx.y;
  const int tile = blockIdx.x;
  const int t = threadIdx.x;
  const bool caseB = (tile >= 32);
  const int a0 = caseB ? (tile - 32) * TM : tile * TM;
  const float* __restrict__ src = img + (size_t)b * (NN * NN);
  const int slope0 = caseB ? (2 * a0) : a0;
  const int dslope = caseB ? 2 : 1;
  float acc[TM];
#pragma unroll
  for (int i = 0; i < TM; ++i) acc[i] = 0.0f;
  for (int y0 = 0; y0 < NN; y0 += YT) {
    __syncthreads();
    if (caseB) {
#pragma unroll
      for (int r = 0; r < YT; ++r) rows[r * LDS_STRIDE + t] = src[(y0 + r) * NN + t];
    } else {
#pragma unroll
      for (int rep = 0; rep < YT; ++rep) {
        int idx = rep * NN + t;
        int xx = idx >> 4, cc = idx & 15;
        rows[cc * LDS_STRIDE + xx] = src[xx * NN + y0 + cc];
      }
    }
    __syncthreads();
#pragma unroll 4
    for (int r = 0; r < YT; ++r) {
      const int v = y0 + r;
      int base = t - slope0 * v;
      const int step = dslope * v;
      const float* __restrict__ rowp = rows + r * LDS_STRIDE;
#pragma unroll
      for (int i = 0; i < TM; ++i) { acc[i] += rowp[base & MASK]; base -= step; }
    }
  }
  const int m = caseB ? (NN + a0) : a0;
  float2* outp = (float2*)out;
#pragma unroll
  for (int i = 0; i < TM; ++i) {
    float2 vv; vv.x = acc[i] * SCALE; vv.y = 0.0f;
    outp[((size_t)b * MU + (m + i)) * NN + t] = vv;
  }
}

extern "C" void kernel_launch(void* const* d_in, const int* in_sizes, int n_in,
                              void* d_out, int out_size, void* d_ws, size_t ws_size,
                              hipStream_t stream) {
  const float* img = (const float*)d_in[0];
  if (ws_size < (size_t)42 * 1024 * 1024) {
    drt_main<<<dim3(48, 16), dim3(512), 0, stream>>>(img, (float*)d_out);
    return;
  }
  float* W  = (float*)d_ws;
  float* A0 = W;                 // 16 x 512 x 512
  float* A1 = W + 4194304;       // 16 x 512 x 512
  float* B1 = W + 8388608;       // 16 x 256 x 512

  k_init_p1b<<<dim3(48, 16), dim3(512), 0, stream>>>(img, A0, B1);
  k_pass1A  <<<dim3(32, 16), dim3(512), 0, stream>>>(A0, A1);
  k_pass2   <<<dim3(48, 16), dim3(512), 0, stream>>>(A1, B1, (float2*)d_out);
}